// Round 14
// baseline (6621.737 us; speedup 1.0000x reference)
//
#include <hip/hip_runtime.h>

#define BATCHES 16
#define NG 2048
#define FDIM 1024
#define EPG 65536
#define NTOT (BATCHES*NG)      // 32768
#define ETOT (BATCHES*EPG)     // 1048576
#define STEPS 64
#define NBLK 1024              // 64 blocks/batch; 4 blocks/CU -> 32 waves/CU
#define NTHR 512
#define WAVES (NTHR/64)        // 8
#define BLK_PER_BATCH (NBLK/BATCHES)          // 64
#define ROWS_PER_BLK (NG/BLK_PER_BATCH)       // 32
#define ROWS_PER_WAVE (ROWS_PER_BLK/WAVES)    // 4
#define EDGE_PER_BLK (ETOT/NBLK)              // 1024
#define EDGES_PER_THR (EDGE_PER_BLK/NTHR)     // 2

// ws layout — byte-identical to the verified round-0/5/7 kernel.
#define WS_XB0   0
#define WS_XB1   (NTOT)
#define WS_PRED  (2*NTOT)
#define WS_COEF  (3*NTOT)
#define WS_QUAD  (3*NTOT + 2*BATCHES*FDIM)
#define WS_LIN   (WS_QUAD + 2*BATCHES)
#define WS_MINR  (WS_LIN + 2*BATCHES)          // u64 cells
#define WS_BAR   (WS_MINR + 2*BATCHES)         // u64 cells (legacy, unused)

// Per-batch barrier state: [batch][0]=arrive, [batch][1]=gen, padded to 64B.
__device__ unsigned long long g_bbar[BATCHES][8];

__device__ __forceinline__ double ld_ag(const double* p) {
    return __hip_atomic_load(p, __ATOMIC_RELAXED, __HIP_MEMORY_SCOPE_AGENT);
}
__device__ __forceinline__ void st_ag(double* p, double v) {
    __hip_atomic_store(p, v, __ATOMIC_RELAXED, __HIP_MEMORY_SCOPE_AGENT);
}
__device__ __forceinline__ unsigned long long ldu64_ag(const unsigned long long* p) {
    return __hip_atomic_load(p, __ATOMIC_RELAXED, __HIP_MEMORY_SCOPE_AGENT);
}
__device__ __forceinline__ void stu64_ag(unsigned long long* p, unsigned long long v) {
    __hip_atomic_store(p, v, __ATOMIC_RELAXED, __HIP_MEMORY_SCOPE_AGENT);
}

// Per-batch barrier (64 participants). PLAIN launch only — cooperative
// launch's occupancy pre-check silently rejects LDS-heavy variants
// (rounds 2-4,6). Residency by capacity: 1024 blocks = 256 CU x 4 exactly
// (25.1KB LDS x4 = 100KB <= 160KB; VGPR <= 64 via launch_bounds).
// NOTE (r11): VGPR cap 64 spills IF per-thread state too big — this round
//   the pred pass is restructured (no c[16] cache) to fit.
// NOTE (r12): coef atomics are write-through — keep 2/thread.
// NOTE (r13): per-thread prefetch arrays spill to scratch — don't.
__device__ __forceinline__ void batch_barrier(unsigned long long* bb,
                                              unsigned long long g, int tid) {
    asm volatile("s_waitcnt vmcnt(0)" ::: "memory");
    __syncthreads();
    if (tid == 0) {
        unsigned long long old = __hip_atomic_fetch_add(
            &bb[0], 1ULL, __ATOMIC_RELAXED, __HIP_MEMORY_SCOPE_AGENT);
        if (old == (unsigned long long)BLK_PER_BATCH * g - 1ULL) {
            stu64_ag(&bb[1], g);
        } else {
            while (ldu64_ag(&bb[1]) < g) __builtin_amdgcn_s_sleep(2);
        }
    }
    __syncthreads();
}

__device__ __forceinline__ double block_reduce_sum(double v, double* s_red) {
    for (int off = 32; off > 0; off >>= 1)
        v += __shfl_down(v, off, 64);
    __syncthreads();
    int lane = threadIdx.x & 63;
    int wave = threadIdx.x >> 6;
    if (lane == 0) s_red[wave] = v;
    __syncthreads();
    double s = 0.0;
    #pragma unroll
    for (int w = 0; w < WAVES; ++w) s += s_red[w];
    return s;
}

__global__ __launch_bounds__(NTHR, 8)   // VGPR cap 64 — code slimmed to fit
void GradSolver_58102317580919_kernel(
    const float* __restrict__ x_start,
    const float* __restrict__ rhs,
    const float* __restrict__ proj,
    const float* __restrict__ q,
    const float* __restrict__ obj_solution,
    const int*   __restrict__ edge_index,
    const float* __restrict__ edge_weight,
    float* __restrict__ out,                // [NTOT bestx][B best][B*STEPS gaps]
    void* __restrict__ wsv)
{
    double* ws = (double*)wsv;
    double* xb[2] = { ws + WS_XB0, ws + WS_XB1 };
    double* pred  = ws + WS_PRED;
    double* coef  = ws + WS_COEF;                    // [2][B*F]
    double* quad  = ws + WS_QUAD;                    // [2][16]
    double* lin   = ws + WS_LIN;                     // [2][16]
    unsigned long long* minr = (unsigned long long*)(ws + WS_MINR); // [2][16]

    const int tid   = threadIdx.x;
    const int bid   = blockIdx.x;
    const int batch = bid / BLK_PER_BATCH;
    const int lbid  = bid % BLK_PER_BATCH;
    const int row_base = batch * NG + lbid * ROWS_PER_BLK;
    const int nbase = batch * NG;
    const int lane  = tid & 63;
    const int wave  = tid >> 6;

    unsigned long long* bb = &g_bbar[batch][0];

    const unsigned long long DINF = 0x7FF0000000000000ULL;

    // LDS: 16K (s_xp) + 8K (s_coef) + 0.75K + ~100B = ~25.1 KB -> 4 blocks/CU.
    __shared__ double s_d[ROWS_PER_BLK];
    __shared__ double s_x[ROWS_PER_BLK];
    __shared__ double s_pred[ROWS_PER_BLK];
    __shared__ double s_coef[FDIM];
    __shared__ double s_xp[NG];                  // batch-wide x_k (alpha folded in)
    __shared__ double s_red[WAVES];
    __shared__ double s_bestobj;

    unsigned long long g = 0;
    double tau = 1.0;

    // ---- edges -> registers ONCE (immutable; 2/thread) ----
    unsigned epk0, epk1;
    float    ew0, ew1;
    {
        const int e0 = bid * EDGE_PER_BLK;
        int ea = e0 + tid, eb = e0 + tid + NTHR;
        epk0 = (unsigned)(edge_index[ea] - nbase) |
               ((unsigned)(edge_index[ETOT + ea] - nbase) << 11);
        epk1 = (unsigned)(edge_index[eb] - nbase) |
               ((unsigned)(edge_index[ETOT + eb] - nbase) << 11);
        ew0 = edge_weight[ea];
        ew1 = edge_weight[eb];
    }

    // ---- P0: zero THIS BATCH's accumulators (batch-local) ----
    // 1024 coef cells per parity / 64 blocks = 16 cells per parity per block
    if (tid < 16) {
        st_ag(&coef[0*(BATCHES*FDIM) + batch*FDIM + lbid*16 + tid], 0.0);
        st_ag(&coef[1*(BATCHES*FDIM) + batch*FDIM + lbid*16 + tid], 0.0);
    }
    if (lbid == 0 && tid == 0) {
        st_ag(&quad[batch], 0.0);      st_ag(&quad[16+batch], 0.0);
        st_ag(&lin[batch],  0.0);      st_ag(&lin[16+batch],  0.0);
        stu64_ag(&minr[batch], DINF);  stu64_ag(&minr[16+batch], DINF);
    }
    if (tid == 0) s_bestobj = __longlong_as_double((long long)DINF);
    batch_barrier(bb, ++g, tid);

    const float2* P2 = (const float2*)(proj + (size_t)row_base * FDIM);

    for (int k = 0; k <= STEPS; ++k) {
        const int p  = k & 1;        // this step's accumulation parity
        const int pp = 1 - p;        // previous step's parity
        // ================= Phase CA =================
        double alpha = 0.0;
        if (k > 0) {
            unsigned long long m = ldu64_ag(&minr[pp*16 + batch]);
            alpha = fmin(__longlong_as_double((long long)m), 1.0) * 0.995;
        }
        double xv = 0.0;
        if (tid < ROWS_PER_BLK) {
            xv = (k == 0) ? (double)x_start[row_base + tid]
                          : s_x[tid] + alpha * s_pred[tid];
            s_x[tid] = xv;
            st_ag(&xb[p][row_base + tid], xv);
            if (k < STEPS)
                s_d[tid] = -xv + (double)rhs[row_base + tid] + 0.1 * tau / (xv + tau);
        }
        tau = fmax(tau * 0.5, 1e-5);

        // stage batch-wide x_k -> LDS (alpha folded; arithmetic identical
        // to the verified per-endpoint expression). Direct loop — no
        // register staging arrays (r13: they spill).
        if (k == 0) {
            #pragma unroll
            for (int j = 0; j < NG/NTHR; ++j) {
                int i = tid + j*NTHR;
                s_xp[i] = (double)x_start[nbase + i];
            }
        } else {
            const double* xprev = xb[pp];
            #pragma unroll
            for (int j = 0; j < NG/NTHR; ++j) {
                int i = tid + j*NTHR;
                s_xp[i] = ld_ag(&xprev[nbase + i]) + alpha * ld_ag(&pred[nbase + i]);
            }
        }

        // resets (batch-local; barrier-separated from readers/writers):
        if (k >= 1 && tid < 16)
            st_ag(&coef[pp*(BATCHES*FDIM) + batch*FDIM + lbid*16 + tid], 0.0);
        if (k < STEPS && lbid == 0 && tid == 0)
            stu64_ag(&minr[p*16 + batch], DINF);

        __syncthreads();   // s_xp (and s_d) complete

        // lin += q . x_k  (rows live in wave 0)
        if (tid < 64) {
            double lp = (tid < ROWS_PER_BLK) ? (double)q[row_base + tid] * xv : 0.0;
            for (int off = 32; off > 0; off >>= 1)
                lp += __shfl_down(lp, off, 64);
            if (tid == 0) unsafeAtomicAdd(&lin[p*16 + batch], lp);
        }

        // quad += w * x_k[s] * x_k[d]  (edges in registers, endpoints in LDS)
        {
            double qp = (double)ew0 * s_xp[epk0 & 2047u] * s_xp[(epk0 >> 11) & 2047u]
                      + (double)ew1 * s_xp[epk1 & 2047u] * s_xp[(epk1 >> 11) & 2047u];
            double qs = block_reduce_sum(qp, s_red);
            if (tid == 0) unsafeAtomicAdd(&quad[p*16 + batch], qs);
        }

        // coef += P^T d   (own rows; float2/thread, 2 atomics/thread)
        if (k < STEPS) {
            double a0 = 0.0, a1 = 0.0;
            #pragma unroll 8
            for (int r = 0; r < ROWS_PER_BLK; ++r) {
                float2 pv = P2[r*(FDIM/2) + tid];
                double dv = s_d[r];
                a0 += (double)pv.x * dv;
                a1 += (double)pv.y * dv;
            }
            double* cf = coef + p*(BATCHES*FDIM) + batch*FDIM + 2*tid;
            unsafeAtomicAdd(cf+0, a0);
            unsafeAtomicAdd(cf+1, a1);
        }
        batch_barrier(bb, ++g, tid);

        // ========= Phase B + pred (pred first — it gates the next step) =========
        double cv0 = 0.0, cv1 = 0.0;
        if (k < STEPS) {
            cv0 = ld_ag(&coef[p*(BATCHES*FDIM) + batch*FDIM + tid]);
            cv1 = ld_ag(&coef[p*(BATCHES*FDIM) + batch*FDIM + tid + NTHR]);
        }
        double qv = ld_ag(&quad[p*16 + batch]);
        double lv = ld_ag(&lin[p*16 + batch]);

        if (k < STEPS) {
            s_coef[tid]        = cv0;
            s_coef[tid + NTHR] = cv1;
            __syncthreads();
            // j-outer / row-inner: each coef quad read from LDS ONCE and
            // applied to this wave's 4 rows (no c[16] register cache — r11
            // spill fix). Named scalars, no runtime-indexed arrays (rule #20).
            const int r0 = wave * ROWS_PER_WAVE;
            const float4* Pr = (const float4*)(proj + (size_t)(row_base + r0) * FDIM);
            double dot0 = 0.0, dot1 = 0.0, dot2 = 0.0, dot3 = 0.0;
            #pragma unroll
            for (int j = 0; j < 4; ++j) {
                const int col = lane + 64*j;
                const int f = 4*col;
                double c0 = s_coef[f+0], c1 = s_coef[f+1];
                double c2 = s_coef[f+2], c3 = s_coef[f+3];
                float4 pv0 = Pr[0*(FDIM/4) + col];
                float4 pv1 = Pr[1*(FDIM/4) + col];
                float4 pv2 = Pr[2*(FDIM/4) + col];
                float4 pv3 = Pr[3*(FDIM/4) + col];
                dot0 += (double)pv0.x*c0 + (double)pv0.y*c1
                      + (double)pv0.z*c2 + (double)pv0.w*c3;
                dot1 += (double)pv1.x*c0 + (double)pv1.y*c1
                      + (double)pv1.z*c2 + (double)pv1.w*c3;
                dot2 += (double)pv2.x*c0 + (double)pv2.y*c1
                      + (double)pv2.z*c2 + (double)pv2.w*c3;
                dot3 += (double)pv3.x*c0 + (double)pv3.y*c1
                      + (double)pv3.z*c2 + (double)pv3.w*c3;
            }
            for (int off = 32; off > 0; off >>= 1) {
                dot0 += __shfl_down(dot0, off, 64);
                dot1 += __shfl_down(dot1, off, 64);
                dot2 += __shfl_down(dot2, off, 64);
                dot3 += __shfl_down(dot3, off, 64);
            }
            if (lane == 0) {
                double wmin = 1e300;
                s_pred[r0+0] = dot0; st_ag(&pred[row_base + r0+0], dot0);
                if (dot0 < 0.0) wmin = fmin(wmin, s_x[r0+0] / (-dot0));
                s_pred[r0+1] = dot1; st_ag(&pred[row_base + r0+1], dot1);
                if (dot1 < 0.0) wmin = fmin(wmin, s_x[r0+1] / (-dot1));
                s_pred[r0+2] = dot2; st_ag(&pred[row_base + r0+2], dot2);
                if (dot2 < 0.0) wmin = fmin(wmin, s_x[r0+2] / (-dot2));
                s_pred[r0+3] = dot3; st_ag(&pred[row_base + r0+3], dot3);
                if (dot3 < 0.0) wmin = fmin(wmin, s_x[r0+3] / (-dot3));
                s_red[wave] = wmin;
            }
        }

        // objective bookkeeping (off the pred critical path)
        double cur = 0.5 * qv + lv;
        double bo  = s_bestobj;
        bool better = cur < bo;
        double nb2 = better ? cur : bo;
        __syncthreads();   // uniform: covers s_red writes + s_bestobj reads
        if (tid == 0) s_bestobj = nb2;
        if (k < STEPS && tid == 0) {
            double m8 = s_red[0];
            #pragma unroll
            for (int w = 1; w < WAVES; ++w) m8 = fmin(m8, s_red[w]);
            atomicMin(&minr[p*16 + batch],
                      (unsigned long long)__double_as_longlong(m8));  // 1 per block
        }
        if (k < STEPS && lbid == 0 && tid == 0) {   // zero next step's accumulators
            st_ag(&quad[pp*16 + batch], 0.0);
            st_ag(&lin[pp*16 + batch],  0.0);
        }
        if (lbid == 0 && tid == 0) {
            double opt = (double)obj_solution[batch];
            double gap = fabs((opt - nb2)/opt);
            if (k >= 1)     out[NTOT + BATCHES + batch*STEPS + (k-1)] = (float)gap;
            if (k == STEPS) out[NTOT + batch] = (float)gap;
        }
        if (better && tid < ROWS_PER_BLK)
            out[row_base + tid] = (float)s_x[tid];

        if (k == STEPS) break;
        batch_barrier(bb, ++g, tid);
    }
}

extern "C" void kernel_launch(void* const* d_in, const int* in_sizes, int n_in,
                              void* d_out, int out_size, void* d_ws, size_t ws_size,
                              hipStream_t stream) {
    const float* x_start      = (const float*)d_in[0];
    const float* rhs          = (const float*)d_in[1];
    const float* proj         = (const float*)d_in[2];
    const float* q            = (const float*)d_in[3];
    const float* obj_solution = (const float*)d_in[4];
    const int*   edge_index   = (const int*)d_in[5];
    const float* edge_weight  = (const float*)d_in[6];
    float* out = (float*)d_out;
    void* ws   = d_ws;

    // zero per-batch barrier state (device symbol — no ws-layout risk)
    void* bbar_ptr = nullptr;
    hipGetSymbolAddress(&bbar_ptr, HIP_SYMBOL(g_bbar));
    hipMemsetAsync(bbar_ptr, 0, sizeof(unsigned long long) * BATCHES * 8, stream);

    // PLAIN launch (see batch_barrier comment).
    hipLaunchKernelGGL(GradSolver_58102317580919_kernel,
                       dim3(NBLK), dim3(NTHR), 0, stream,
                       x_start, rhs, proj, q, obj_solution,
                       edge_index, edge_weight, out, ws);
}

// Round 15
// 5533.942 us; speedup vs baseline: 1.1966x; 1.1966x over previous
//
#include <hip/hip_runtime.h>

#define BATCHES 16
#define NG 2048
#define FDIM 1024
#define EPG 65536
#define NTOT (BATCHES*NG)      // 32768
#define ETOT (BATCHES*EPG)     // 1048576
#define STEPS 64
#define NBLK 512               // 32 blocks/batch; 2 blocks/CU (LDS-bound)
#define NTHR 512
#define WAVES (NTHR/64)        // 8
#define BLK_PER_BATCH (NBLK/BATCHES)          // 32
#define ROWS_PER_BLK (NG/BLK_PER_BATCH)       // 64
#define EDGE_PER_BLK (ETOT/NBLK)              // 2048
#define EDGES_PER_THR (EDGE_PER_BLK/NTHR)     // 4
#define REGROWS 32                            // proj rows held in registers

// ws layout — byte-identical to the verified round-0/5/7 kernel.
#define WS_XB0   0
#define WS_XB1   (NTOT)
#define WS_PRED  (2*NTOT)
#define WS_COEF  (3*NTOT)
#define WS_QUAD  (3*NTOT + 2*BATCHES*FDIM)
#define WS_LIN   (WS_QUAD + 2*BATCHES)
#define WS_MINR  (WS_LIN + 2*BATCHES)          // u64 cells
#define WS_BAR   (WS_MINR + 2*BATCHES)         // u64 cells (legacy, unused)

// Per-batch barrier state: [batch][0]=arrive, [batch][1]=gen, padded to 64B.
__device__ unsigned long long g_bbar[BATCHES][8];

__device__ __forceinline__ double ld_ag(const double* p) {
    return __hip_atomic_load(p, __ATOMIC_RELAXED, __HIP_MEMORY_SCOPE_AGENT);
}
__device__ __forceinline__ void st_ag(double* p, double v) {
    __hip_atomic_store(p, v, __ATOMIC_RELAXED, __HIP_MEMORY_SCOPE_AGENT);
}
__device__ __forceinline__ unsigned long long ldu64_ag(const unsigned long long* p) {
    return __hip_atomic_load(p, __ATOMIC_RELAXED, __HIP_MEMORY_SCOPE_AGENT);
}
__device__ __forceinline__ void stu64_ag(unsigned long long* p, unsigned long long v) {
    __hip_atomic_store(p, v, __ATOMIC_RELAXED, __HIP_MEMORY_SCOPE_AGENT);
}

// Per-batch barrier (32 participants). PLAIN launch only — cooperative
// launch's occupancy pre-check silently rejects LDS-heavy variants
// (rounds 2-4,6). Co-residency by capacity: 2 blocks/CU x ~22KB LDS.
// NOTE (r11/r14): requesting 8 waves/EU spills (VGPR 32 + scratch). Stay
//   at bounds(512,4): LDS-bound at 2 blocks/CU, so up to 128 VGPR is free.
// NOTE (r12): coef atomics are write-through — keep 2/thread.
// NOTE (r13): runtime-indexed per-thread arrays spill — proj rows below
//   are individually NAMED registers via X-macro (rule #20).
__device__ __forceinline__ void batch_barrier(unsigned long long* bb,
                                              unsigned long long g, int tid) {
    asm volatile("s_waitcnt vmcnt(0)" ::: "memory");
    __syncthreads();
    if (tid == 0) {
        unsigned long long old = __hip_atomic_fetch_add(
            &bb[0], 1ULL, __ATOMIC_RELAXED, __HIP_MEMORY_SCOPE_AGENT);
        if (old == (unsigned long long)BLK_PER_BATCH * g - 1ULL) {
            stu64_ag(&bb[1], g);
        } else {
            while (ldu64_ag(&bb[1]) < g) __builtin_amdgcn_s_sleep(2);
        }
    }
    __syncthreads();
}

__device__ __forceinline__ double block_reduce_sum(double v, double* s_red) {
    for (int off = 32; off > 0; off >>= 1)
        v += __shfl_down(v, off, 64);
    __syncthreads();
    int lane = threadIdx.x & 63;
    int wave = threadIdx.x >> 6;
    if (lane == 0) s_red[wave] = v;
    __syncthreads();
    double s = 0.0;
    #pragma unroll
    for (int w = 0; w < WAVES; ++w) s += s_red[w];
    return s;
}

// per-row column-reduce: cr = this thread's 2-col contribution to row r;
// 6-level wave reduce, lane 0 deposits the wave partial.
__device__ __forceinline__ void row_reduce(double cr, int r, int lane, int wave,
                                           double* s_pp) {
    for (int off = 32; off > 0; off >>= 1)
        cr += __shfl_down(cr, off, 64);
    if (lane == 0) s_pp[wave*ROWS_PER_BLK + r] = cr;
}

// X-macro over the 32 register-resident proj rows (rule #20: named, not array)
#define R32(M) M(0) M(1) M(2) M(3) M(4) M(5) M(6) M(7) M(8) M(9) M(10) M(11) \
    M(12) M(13) M(14) M(15) M(16) M(17) M(18) M(19) M(20) M(21) M(22) M(23) \
    M(24) M(25) M(26) M(27) M(28) M(29) M(30) M(31)

__global__ __launch_bounds__(NTHR, 4)   // VGPR cap 128 (LDS-bound: free headroom)
void GradSolver_58102317580919_kernel(
    const float* __restrict__ x_start,
    const float* __restrict__ rhs,
    const float* __restrict__ proj,
    const float* __restrict__ q,
    const float* __restrict__ obj_solution,
    const int*   __restrict__ edge_index,
    const float* __restrict__ edge_weight,
    float* __restrict__ out,                // [NTOT bestx][B best][B*STEPS gaps]
    void* __restrict__ wsv)
{
    double* ws = (double*)wsv;
    double* xb[2] = { ws + WS_XB0, ws + WS_XB1 };
    double* pred  = ws + WS_PRED;
    double* coef  = ws + WS_COEF;                    // [2][B*F]
    double* quad  = ws + WS_QUAD;                    // [2][16]
    double* lin   = ws + WS_LIN;                     // [2][16]
    unsigned long long* minr = (unsigned long long*)(ws + WS_MINR); // [2][16]

    const int tid   = threadIdx.x;
    const int bid   = blockIdx.x;
    const int batch = bid / BLK_PER_BATCH;
    const int lbid  = bid % BLK_PER_BATCH;
    const int row_base = batch * NG + lbid * ROWS_PER_BLK;
    const int nbase = batch * NG;
    const int lane  = tid & 63;
    const int wave  = tid >> 6;

    unsigned long long* bb = &g_bbar[batch][0];

    const unsigned long long DINF = 0x7FF0000000000000ULL;

    // LDS: 16K (s_xp) + 4K (s_pp) + 1.5K + ~100B = ~21.7 KB -> 2 blocks/CU.
    __shared__ double s_d[ROWS_PER_BLK];
    __shared__ double s_x[ROWS_PER_BLK];
    __shared__ double s_pred[ROWS_PER_BLK];
    __shared__ double s_xp[NG];                  // batch-wide x_k (alpha folded in)
    __shared__ double s_pp[WAVES*ROWS_PER_BLK];  // pass-2 wave partials
    __shared__ double s_red[WAVES];
    __shared__ double s_bestobj;

    unsigned long long g = 0;
    double tau = 1.0;

    const float2* P2 = (const float2*)(proj + (size_t)row_base * FDIM);

    // ---- proj rows 0..31 -> NAMED registers ONCE (proj is constant).
    // Thread t owns columns 2t, 2t+1 of every row. 64 VGPRs, resident forever.
    #define DECLR(i) float2 pr##i = P2[(i)*(FDIM/2) + tid];
    R32(DECLR)
    #undef DECLR

    // ---- edges -> registers ONCE (immutable; 4/thread) ----
    unsigned epk[EDGES_PER_THR];
    float    ew[EDGES_PER_THR];
    {
        const int e0 = bid * EDGE_PER_BLK;
        #pragma unroll
        for (int j = 0; j < EDGES_PER_THR; ++j) {
            int e = e0 + tid + j*NTHR;
            unsigned si = (unsigned)(edge_index[e]        - nbase);  // < 2048
            unsigned di = (unsigned)(edge_index[ETOT + e] - nbase);
            epk[j] = si | (di << 11);
            ew[j]  = edge_weight[e];
        }
    }

    // ---- P0: zero THIS BATCH's accumulators (batch-local) ----
    if (tid < 32) {
        st_ag(&coef[0*(BATCHES*FDIM) + batch*FDIM + lbid*32 + tid], 0.0);
        st_ag(&coef[1*(BATCHES*FDIM) + batch*FDIM + lbid*32 + tid], 0.0);
    }
    if (lbid == 0 && tid == 0) {
        st_ag(&quad[batch], 0.0);      st_ag(&quad[16+batch], 0.0);
        st_ag(&lin[batch],  0.0);      st_ag(&lin[16+batch],  0.0);
        stu64_ag(&minr[batch], DINF);  stu64_ag(&minr[16+batch], DINF);
    }
    if (tid == 0) s_bestobj = __longlong_as_double((long long)DINF);
    batch_barrier(bb, ++g, tid);

    for (int k = 0; k <= STEPS; ++k) {
        const int p  = k & 1;        // this step's accumulation parity
        const int pp = 1 - p;        // previous step's parity
        // ================= Phase CA =================
        double alpha = 0.0;
        if (k > 0) {
            unsigned long long m = ldu64_ag(&minr[pp*16 + batch]);
            alpha = fmin(__longlong_as_double((long long)m), 1.0) * 0.995;
        }
        double xv = 0.0;
        if (tid < ROWS_PER_BLK) {
            xv = (k == 0) ? (double)x_start[row_base + tid]
                          : s_x[tid] + alpha * s_pred[tid];
            s_x[tid] = xv;
            st_ag(&xb[p][row_base + tid], xv);
            if (k < STEPS)
                s_d[tid] = -xv + (double)rhs[row_base + tid] + 0.1 * tau / (xv + tau);
        }
        tau = fmax(tau * 0.5, 1e-5);

        // stage batch-wide x_k -> LDS (alpha folded; arithmetic identical
        // to the verified per-endpoint expression). Direct — no reg arrays.
        if (k == 0) {
            #pragma unroll
            for (int j = 0; j < NG/NTHR; ++j) {
                int i = tid + j*NTHR;
                s_xp[i] = (double)x_start[nbase + i];
            }
        } else {
            const double* xprev = xb[pp];
            #pragma unroll
            for (int j = 0; j < NG/NTHR; ++j) {
                int i = tid + j*NTHR;
                s_xp[i] = ld_ag(&xprev[nbase + i]) + alpha * ld_ag(&pred[nbase + i]);
            }
        }

        // resets (batch-local; barrier-separated from readers/writers):
        if (k >= 1 && tid < 32)
            st_ag(&coef[pp*(BATCHES*FDIM) + batch*FDIM + lbid*32 + tid], 0.0);
        if (k < STEPS && lbid == 0 && tid == 0)
            stu64_ag(&minr[p*16 + batch], DINF);

        __syncthreads();   // s_xp (and s_d) complete

        // lin += q . x_k  (all 64 rows live in wave 0)
        if (tid < 64) {
            double lp = (double)q[row_base + tid] * xv;
            for (int off = 32; off > 0; off >>= 1)
                lp += __shfl_down(lp, off, 64);
            if (tid == 0) unsafeAtomicAdd(&lin[p*16 + batch], lp);
        }

        // quad += w * x_k[s] * x_k[d]  (edges in registers, endpoints in LDS)
        {
            double qp = 0.0;
            #pragma unroll
            for (int j = 0; j < EDGES_PER_THR; ++j) {
                unsigned pk = epk[j];
                qp += (double)ew[j] * s_xp[pk & 2047u] * s_xp[(pk >> 11) & 2047u];
            }
            double qs = block_reduce_sum(qp, s_red);
            if (tid == 0) unsafeAtomicAdd(&quad[p*16 + batch], qs);
        }

        // coef += P^T d: rows 0..31 from REGISTERS (zero memory), rows 32..63
        // streamed. Same accumulation order as champion. 2 atomics/thread.
        if (k < STEPS) {
            double a0 = 0.0, a1 = 0.0;
            #define P1R(i) { double dv = s_d[i]; \
                a0 += (double)pr##i.x * dv; a1 += (double)pr##i.y * dv; }
            R32(P1R)
            #undef P1R
            #pragma unroll 8
            for (int r = REGROWS; r < ROWS_PER_BLK; ++r) {
                float2 pv = P2[r*(FDIM/2) + tid];
                double dv = s_d[r];
                a0 += (double)pv.x * dv;
                a1 += (double)pv.y * dv;
            }
            double* cf = coef + p*(BATCHES*FDIM) + batch*FDIM + 2*tid;
            unsafeAtomicAdd(cf+0, a0);
            unsafeAtomicAdd(cf+1, a1);
        }
        batch_barrier(bb, ++g, tid);

        // ========= pred (column-wise; same register layout as pass 1) =========
        double c0 = 0.0, c1 = 0.0;
        if (k < STEPS) {
            c0 = ld_ag(&coef[p*(BATCHES*FDIM) + batch*FDIM + 2*tid]);
            c1 = ld_ag(&coef[p*(BATCHES*FDIM) + batch*FDIM + 2*tid + 1]);
        }
        double qv = ld_ag(&quad[p*16 + batch]);
        double lv = ld_ag(&lin[p*16 + batch]);

        if (k < STEPS) {
            // rows 0..31 from registers (zero memory traffic)
            #define P2R(i) { double cr = (double)pr##i.x * c0 + (double)pr##i.y * c1; \
                row_reduce(cr, i, lane, wave, s_pp); }
            R32(P2R)
            #undef P2R
            // rows 32..63 streamed (L2-warm: pass 1 read them just before barrier)
            #pragma unroll 4
            for (int r = REGROWS; r < ROWS_PER_BLK; ++r) {
                float2 pv = P2[r*(FDIM/2) + tid];
                double cr = (double)pv.x * c0 + (double)pv.y * c1;
                row_reduce(cr, r, lane, wave, s_pp);
            }
        }

        // objective bookkeeping (read s_bestobj before the sync)
        double cur = 0.5 * qv + lv;
        double bo  = s_bestobj;
        bool better = cur < bo;
        double nb2 = better ? cur : bo;
        __syncthreads();   // uniform: covers s_pp writes + s_bestobj reads
        if (tid == 0) s_bestobj = nb2;

        // finalize pred: thread r sums the 8 wave partials for its row
        if (k < STEPS) {
            double wmin = 1e300;
            if (tid < ROWS_PER_BLK) {
                double pr_ = 0.0;
                #pragma unroll
                for (int w = 0; w < WAVES; ++w) pr_ += s_pp[w*ROWS_PER_BLK + tid];
                s_pred[tid] = pr_;
                st_ag(&pred[row_base + tid], pr_);
                if (pr_ < 0.0) wmin = fmin(wmin, s_x[tid] / (-pr_));
            }
            if (tid < 64) {
                for (int off = 32; off > 0; off >>= 1)
                    wmin = fmin(wmin, __shfl_down(wmin, off, 64));
                if (tid == 0)
                    atomicMin(&minr[p*16 + batch],
                              (unsigned long long)__double_as_longlong(wmin));
            }
        }
        if (k < STEPS && lbid == 0 && tid == 0) {   // zero next step's accumulators
            st_ag(&quad[pp*16 + batch], 0.0);
            st_ag(&lin[pp*16 + batch],  0.0);
        }
        if (lbid == 0 && tid == 0) {
            double opt = (double)obj_solution[batch];
            double gap = fabs((opt - nb2)/opt);
            if (k >= 1)     out[NTOT + BATCHES + batch*STEPS + (k-1)] = (float)gap;
            if (k == STEPS) out[NTOT + batch] = (float)gap;
        }
        if (better && tid < ROWS_PER_BLK)
            out[row_base + tid] = (float)s_x[tid];

        if (k == STEPS) break;
        batch_barrier(bb, ++g, tid);
    }
}

extern "C" void kernel_launch(void* const* d_in, const int* in_sizes, int n_in,
                              void* d_out, int out_size, void* d_ws, size_t ws_size,
                              hipStream_t stream) {
    const float* x_start      = (const float*)d_in[0];
    const float* rhs          = (const float*)d_in[1];
    const float* proj         = (const float*)d_in[2];
    const float* q            = (const float*)d_in[3];
    const float* obj_solution = (const float*)d_in[4];
    const int*   edge_index   = (const int*)d_in[5];
    const float* edge_weight  = (const float*)d_in[6];
    float* out = (float*)d_out;
    void* ws   = d_ws;

    // zero per-batch barrier state (device symbol — no ws-layout risk)
    void* bbar_ptr = nullptr;
    hipGetSymbolAddress(&bbar_ptr, HIP_SYMBOL(g_bbar));
    hipMemsetAsync(bbar_ptr, 0, sizeof(unsigned long long) * BATCHES * 8, stream);

    // PLAIN launch (see batch_barrier comment).
    hipLaunchKernelGGL(GradSolver_58102317580919_kernel,
                       dim3(NBLK), dim3(NTHR), 0, stream,
                       x_start, rhs, proj, q, obj_solution,
                       edge_index, edge_weight, out, ws);
}